// Round 5
// baseline (100.589 us; speedup 1.0000x reference)
//
#include <hip/hip_runtime.h>

// Problem constants (B=2, H=4 -> NBH=8; Tq=Tk=512; D=64; HID=128)
#define T    512
#define D    64
#define HID  128
#define NBH  8
#define NP   (HID / 2)   // 64 c-pairs

typedef _Float16 h2 __attribute__((ext_vector_type(2)));

static __device__ __forceinline__ h2 bc_h2(float f) {
    return __builtin_bit_cast(h2, f);
}

// Guaranteed single v_pk_max_f16 (relu on a packed f16 pair).
static __device__ __forceinline__ h2 relu_h2(h2 x) {
    h2 r;
    asm("v_pk_max_f16 %0, %1, 0" : "=v"(r) : "v"(x));
    return r;
}

// ---------------------------------------------------------------------------
// Phase A: qh[bh][c][i] = b1[c] + sum_d q[bh][i][d] * W1[d][c]   (src==0)
//          kh[bh][c][j] =         sum_d k[bh][j][d] * W1[64+d][c] (src==1)
// NO LDS: W1 is read with a wave-uniform address (readfirstlane on the wave
// id makes the 8-channel base provably uniform) -> compiler emits
// s_load_dwordx4 into SGPRs; the inner loop is v_fma with a scalar operand.
// R4's version spent 1536 LDS-pipe cyc/wave on broadcast ds_read_b128 of the
// staged W1 rows (5.1 us/CU at 8 waves) -- that pipe cost is now zero.
// Block 0 additionally packs W2 (fp32) into h2 pairs in global ws for the
// score kernel's scalar w-loads.
// grid: 8 bh x 2 src x 8 row-chunks x 4 c-splits = 512 blocks (2/CU).
// ---------------------------------------------------------------------------
__global__ __launch_bounds__(256, 2) void proj_kernel(
    const float* __restrict__ q, const float* __restrict__ k,
    const float* __restrict__ W1, const float* __restrict__ b1,
    const float* __restrict__ W2,
    h2* __restrict__ qh_h, h2* __restrict__ kh_h, h2* __restrict__ w2g)
{
    const int bid    = blockIdx.x;        // [0,512)
    const int bh     = bid >> 6;
    const int src    = (bid >> 5) & 1;
    const int chunk  = (bid >> 2) & 7;
    const int csplit = bid & 3;           // 32 channels per block
    const int tid    = threadIdx.x;

    // Pack W2 -> h2 once (score reads it via uniform s_load).
    if (bid == 0 && tid < NP) {
        h2 w;
        w.x = (_Float16)W2[2 * tid];
        w.y = (_Float16)W2[2 * tid + 1];
        w2g[tid] = w;
    }

    const int r   = tid & 63;                                   // lane -> i row
    const int cgu = __builtin_amdgcn_readfirstlane(tid >> 6);   // wave-uniform
    const int c0  = csplit * 32 + cgu * 8;                      // uniform base

    const float* __restrict__ X = (src == 0) ? q : k;
    h2* __restrict__ outp       = (src == 0) ? qh_h : kh_h;
    const int i = chunk * 64 + r;

    // This thread's input row in registers (64 VGPR).
    float xr[D];
    const float4* xrow = (const float4*)(X + (size_t)(bh * T + i) * D);
    #pragma unroll
    for (int t = 0; t < D / 4; ++t) {
        const float4 v = xrow[t];
        xr[4*t+0] = v.x; xr[4*t+1] = v.y; xr[4*t+2] = v.z; xr[4*t+3] = v.w;
    }

    float acc[8];
    #pragma unroll
    for (int cc = 0; cc < 8; ++cc)
        acc[cc] = (src == 0) ? b1[c0 + cc] : 0.0f;   // uniform -> s_load

    // Uniform W1 pointer: s_load_dwordx4 pairs per d; v_fma with SGPR src.
    const float* __restrict__ w1base = W1 + (size_t)src * D * HID + c0;
    #pragma unroll 8
    for (int d = 0; d < D; ++d) {
        const float4 wa = *(const float4*)(w1base + (size_t)d * HID);
        const float4 wb = *(const float4*)(w1base + (size_t)d * HID + 4);
        const float x = xr[d];
        acc[0] += x * wa.x; acc[1] += x * wa.y;
        acc[2] += x * wa.z; acc[3] += x * wa.w;
        acc[4] += x * wb.x; acc[5] += x * wb.y;
        acc[6] += x * wb.z; acc[7] += x * wb.w;
    }

    #pragma unroll
    for (int pp = 0; pp < 4; ++pp) {
        h2 v;
        v.x = (_Float16)acc[2 * pp];
        v.y = (_Float16)acc[2 * pp + 1];
        const int p = (c0 >> 1) + pp;                 // pair index [0,64)
        outp[(size_t)(bh * NP + p) * T + i] = v;      // lanes span i: coalesced
    }
}

// ---------------------------------------------------------------------------
// Phase B: s[bh][i][j] = b2 + sum_c W2[c] * relu(qh[bh][c][i] + kh[bh][c][j])
// 64x64 tile, 256 threads, 4x4 fp32 acc/thread (best-measured geometry, R3).
// Inner: per c-pair per cell: v_pk_add_f16 + v_pk_max_f16 + v_dot2_f32_f16.
// w2 comes from GLOBAL with a loop-uniform index -> s_load (SGPR operand in
// the dot2), removing R2-R4's per-p ds_read_b32 of w2h (~15% of LDS traffic).
// LDS per p per wave: exactly 2x ds_read_b128.
// grid: 8 bh x 8 it x 8 jt = 512 blocks, LDS 32 KB -> 2 blocks/CU.
// ---------------------------------------------------------------------------
__global__ __launch_bounds__(256, 2) void score_kernel(
    const h2* __restrict__ qh_h, const h2* __restrict__ kh_h,
    const h2* __restrict__ w2g, const float* __restrict__ b2,
    float* __restrict__ out)
{
    const int bid = blockIdx.x;           // [0, 512)
    const int bh  = bid >> 6;
    const int it  = (bid >> 3) & 7;
    const int jt  = bid & 7;
    const int i0  = it * 64;
    const int j0  = jt * 64;

    __shared__ h2 qt2[NP][64];            // 16 KB
    __shared__ h2 kt2[NP][64];            // 16 KB

    const int tid = threadIdx.x;
    // Stage both tiles: 2 x 64 rows x 16 float4 (256 B coalesced per row).
    for (int idx = tid; idx < 2 * NP * 16; idx += 256) {
        const int tile = idx >> 10;
        const int p    = (idx >> 4) & 63;
        const int g    = idx & 15;
        const h2* srcp = tile ? kh_h : qh_h;
        const int o0   = tile ? j0 : i0;
        float4 v = ((const float4*)(srcp + (size_t)(bh * NP + p) * T + o0))[g];
        if (tile) ((float4*)&kt2[p][0])[g] = v;
        else      ((float4*)&qt2[p][0])[g] = v;
    }
    __syncthreads();

    const int tx = tid & 15;              // j fragment (4 j's)
    const int ty = tid >> 4;              // i fragment (4 i's)

    float acc[4][4];
    #pragma unroll
    for (int m = 0; m < 4; ++m)
        #pragma unroll
        for (int n = 0; n < 4; ++n)
            acc[m][n] = 0.0f;

    #pragma unroll 8
    for (int p = 0; p < NP; ++p) {
        const h2 w = w2g[p];                                 // uniform s_load
        const float4 qa4 = ((const float4*)&qt2[p][0])[ty];  // 4 h2: i..i+3
        const float4 kb4 = ((const float4*)&kt2[p][0])[tx];  // 4 h2: j..j+3
        const h2 qv[4] = {bc_h2(qa4.x), bc_h2(qa4.y), bc_h2(qa4.z), bc_h2(qa4.w)};
        const h2 kv[4] = {bc_h2(kb4.x), bc_h2(kb4.y), bc_h2(kb4.z), bc_h2(kb4.w)};
        #pragma unroll
        for (int m = 0; m < 4; ++m) {
            #pragma unroll
            for (int n = 0; n < 4; ++n) {
                h2 u = qv[m] + kv[n];                 // v_pk_add_f16
                u = relu_h2(u);                       // v_pk_max_f16
                acc[m][n] = __builtin_amdgcn_fdot2(u, w, acc[m][n], false);
            }
        }
    }

    const float bb = b2[0];
    #pragma unroll
    for (int m = 0; m < 4; ++m) {
        const int i = i0 + 4 * ty + m;
        float4 o;
        o.x = acc[m][0] + bb;
        o.y = acc[m][1] + bb;
        o.z = acc[m][2] + bb;
        o.w = acc[m][3] + bb;
        ((float4*)(out + (size_t)(bh * T + i) * T + j0))[tx] = o;
    }
}

extern "C" void kernel_launch(void* const* d_in, const int* in_sizes, int n_in,
                              void* d_out, int out_size, void* d_ws, size_t ws_size,
                              hipStream_t stream) {
    const float* q  = (const float*)d_in[0];
    const float* k  = (const float*)d_in[1];
    const float* W1 = (const float*)d_in[2];
    const float* b1 = (const float*)d_in[3];
    const float* W2 = (const float*)d_in[4];
    const float* b2 = (const float*)d_in[5];
    float* out = (float*)d_out;

    // Workspace: qh_h + kh_h (1 MB each) + packed w2 (256 B).
    h2* qh_h = (h2*)d_ws;
    h2* kh_h = qh_h + (size_t)NBH * NP * T;
    h2* w2g  = kh_h + (size_t)NBH * NP * T;

    proj_kernel<<<512, 256, 0, stream>>>(q, k, W1, b1, W2, qh_h, kh_h, w2g);
    score_kernel<<<512, 256, 0, stream>>>(qh_h, kh_h, w2g, b2, out);
}

// Round 6
// 91.837 us; speedup vs baseline: 1.0953x; 1.0953x over previous
//
#include <hip/hip_runtime.h>

// Problem constants (B=2, H=4 -> NBH=8; Tq=Tk=512; D=64; HID=128)
#define T    512
#define D    64
#define HID  128
#define NBH  8
#define NP   (HID / 2)   // 64 c-pairs

typedef _Float16 h2 __attribute__((ext_vector_type(2)));

static __device__ __forceinline__ h2 bc_h2(float f) {
    return __builtin_bit_cast(h2, f);
}

// ---------------------------------------------------------------------------
// Phase A (identical to the best-measured R3 version): LDS-staged W1.
// qh[bh][c][i] = b1[c] + sum_d q[bh][i][d] * W1[d][c]   (src==0)
// kh[bh][c][j] =         sum_d k[bh][j][d] * W1[64+d][c] (src==1)
// Output packed as h2 pairs over c: ws[bh][p][i], i contiguous.
// grid: 8 bh x 2 src x 8 row-chunks x 4 c-splits = 512 blocks (2/CU).
// ---------------------------------------------------------------------------
__global__ __launch_bounds__(256, 2) void proj_kernel(
    const float* __restrict__ q, const float* __restrict__ k,
    const float* __restrict__ W1, const float* __restrict__ b1,
    h2* __restrict__ qh_h, h2* __restrict__ kh_h)
{
    const int bid    = blockIdx.x;        // [0,512)
    const int bh     = bid >> 6;
    const int src    = (bid >> 5) & 1;
    const int chunk  = (bid >> 2) & 7;
    const int csplit = bid & 3;
    const int base_c = csplit * 32;       // 32 channels per block

    const float* __restrict__ X = (src == 0) ? q : k;
    h2* __restrict__ outp       = (src == 0) ? qh_h : kh_h;

    // 32 c-rows of W1, transposed to [cc][d]; stride 68 floats keeps 16 B
    // alignment (272 B) and breaks pow-2 bank stride on staging writes.
    __shared__ float w1t[32][68];

    const int tid = threadIdx.x;
    for (int idx = tid; idx < 32 * 64; idx += 256) {
        const int cc = idx & 31;          // consecutive -> coalesced global read
        const int d  = idx >> 5;
        w1t[cc][d] = W1[(src * D + d) * HID + base_c + cc];
    }
    __syncthreads();

    const int r  = tid & 63;              // lane -> row (stores coalesce)
    const int cg = tid >> 6;              // wave -> 8-c group (wave-uniform)
    const int i  = chunk * 64 + r;

    // This thread's input row in registers (64 VGPR).
    float xr[D];
    const float4* xrow = (const float4*)(X + (size_t)(bh * T + i) * D);
    #pragma unroll
    for (int t = 0; t < D / 4; ++t) {
        const float4 v = xrow[t];
        xr[4*t+0] = v.x; xr[4*t+1] = v.y; xr[4*t+2] = v.z; xr[4*t+3] = v.w;
    }

    #pragma unroll
    for (int pp = 0; pp < 4; ++pp) {
        const int cc0 = cg * 8 + 2 * pp;         // wave-uniform -> LDS broadcast
        float acc0 = (src == 0) ? b1[base_c + cc0]     : 0.0f;
        float acc1 = (src == 0) ? b1[base_c + cc0 + 1] : 0.0f;
        const float4* w0 = (const float4*)(&w1t[cc0][0]);
        const float4* w1 = (const float4*)(&w1t[cc0 + 1][0]);
        #pragma unroll
        for (int t = 0; t < D / 4; ++t) {
            const float4 a = w0[t];
            const float4 b = w1[t];
            acc0 += xr[4*t+0]*a.x + xr[4*t+1]*a.y + xr[4*t+2]*a.z + xr[4*t+3]*a.w;
            acc1 += xr[4*t+0]*b.x + xr[4*t+1]*b.y + xr[4*t+2]*b.z + xr[4*t+3]*b.w;
        }
        h2 v;
        v.x = (_Float16)acc0;
        v.y = (_Float16)acc1;
        const int p = csplit * 16 + cg * 4 + pp;  // global pair index [0,64)
        outp[(size_t)(bh * NP + p) * T + i] = v;  // lanes span i -> coalesced
    }
}

// ---------------------------------------------------------------------------
// Phase B: s[bh][i][j] = b2 + sum_c W2[c] * relu(qh[bh][c][i] + kh[bh][c][j])
// 64x64 tile, 256 threads, 4x4 fp32 acc/thread (best-measured geometry).
// INNER OPS PINNED VIA INLINE ASM: exactly one v_pk_add_f16 + one
// v_pk_max_f16 + one v_dot2_f32_f16 per c-pair per cell (3 instr / 2 MACs).
// Separate non-volatile asm statements -> scheduler can still interleave the
// 16 independent cell chains. This tests the scalarization hypothesis: if
// the h2 '+' was legalizing to 2x v_add_f16, this removes ~1/3 of inner
// VALU instructions.
// w2 staged in LDS, read as float4 once per 4 p (amortized b128).
// grid: 8 bh x 8 it x 8 jt = 512 blocks, LDS 32.3 KB -> 2 blocks/CU.
// ---------------------------------------------------------------------------
__global__ __launch_bounds__(256, 2) void score_kernel(
    const h2* __restrict__ qh_h, const h2* __restrict__ kh_h,
    const float* __restrict__ W2, const float* __restrict__ b2,
    float* __restrict__ out)
{
    const int bid = blockIdx.x;           // [0, 512)
    const int bh  = bid >> 6;
    const int it  = (bid >> 3) & 7;
    const int jt  = bid & 7;
    const int i0  = it * 64;
    const int j0  = jt * 64;

    __shared__ h2 qt2[NP][64];            // 16 KB
    __shared__ h2 kt2[NP][64];            // 16 KB
    __shared__ h2 w2h[NP];                // 256 B

    const int tid = threadIdx.x;
    // Stage both tiles: 2 x 64 rows x 16 float4 (256 B coalesced per row).
    for (int idx = tid; idx < 2 * NP * 16; idx += 256) {
        const int tile = idx >> 10;
        const int p    = (idx >> 4) & 63;
        const int g    = idx & 15;
        const h2* srcp = tile ? kh_h : qh_h;
        const int o0   = tile ? j0 : i0;
        float4 v = ((const float4*)(srcp + (size_t)(bh * NP + p) * T + o0))[g];
        if (tile) ((float4*)&kt2[p][0])[g] = v;
        else      ((float4*)&qt2[p][0])[g] = v;
    }
    if (tid < NP) {
        h2 w;
        w.x = (_Float16)W2[2 * tid];
        w.y = (_Float16)W2[2 * tid + 1];
        w2h[tid] = w;
    }
    __syncthreads();

    const int tx = tid & 15;              // j fragment (4 j's)
    const int ty = tid >> 4;              // i fragment (4 i's)

    float acc[4][4];
    #pragma unroll
    for (int m = 0; m < 4; ++m)
        #pragma unroll
        for (int n = 0; n < 4; ++n)
            acc[m][n] = 0.0f;

    for (int pg = 0; pg < 16; ++pg) {
        // One b128 per 4 c-pairs for the w2 values.
        const float4 w4 = ((const float4*)&w2h[0])[pg];
        #pragma unroll
        for (int s = 0; s < 4; ++s) {
            const int p = 4 * pg + s;
            const h2 w = bc_h2(s == 0 ? w4.x : s == 1 ? w4.y
                             : s == 2 ? w4.z : w4.w);
            const float4 qa4 = ((const float4*)&qt2[p][0])[ty];  // 4 h2: i..i+3
            const float4 kb4 = ((const float4*)&kt2[p][0])[tx];  // 4 h2: j..j+3
            const h2 qv[4] = {bc_h2(qa4.x), bc_h2(qa4.y),
                              bc_h2(qa4.z), bc_h2(qa4.w)};
            const h2 kv[4] = {bc_h2(kb4.x), bc_h2(kb4.y),
                              bc_h2(kb4.z), bc_h2(kb4.w)};
            #pragma unroll
            for (int m = 0; m < 4; ++m) {
                #pragma unroll
                for (int n = 0; n < 4; ++n) {
                    h2 u, r;
                    asm("v_pk_add_f16 %0, %1, %2"
                        : "=v"(u) : "v"(qv[m]), "v"(kv[n]));
                    asm("v_pk_max_f16 %0, %1, 0"
                        : "=v"(r) : "v"(u));
                    asm("v_dot2_f32_f16 %0, %1, %2, %0"
                        : "+v"(acc[m][n]) : "v"(r), "v"(w));
                }
            }
        }
    }

    const float bb = b2[0];
    #pragma unroll
    for (int m = 0; m < 4; ++m) {
        const int i = i0 + 4 * ty + m;
        float4 o;
        o.x = acc[m][0] + bb;
        o.y = acc[m][1] + bb;
        o.z = acc[m][2] + bb;
        o.w = acc[m][3] + bb;
        ((float4*)(out + (size_t)(bh * T + i) * T + j0))[tx] = o;
    }
}

extern "C" void kernel_launch(void* const* d_in, const int* in_sizes, int n_in,
                              void* d_out, int out_size, void* d_ws, size_t ws_size,
                              hipStream_t stream) {
    const float* q  = (const float*)d_in[0];
    const float* k  = (const float*)d_in[1];
    const float* W1 = (const float*)d_in[2];
    const float* b1 = (const float*)d_in[3];
    const float* W2 = (const float*)d_in[4];
    const float* b2 = (const float*)d_in[5];
    float* out = (float*)d_out;

    // Workspace: qh_h + kh_h as h2 pairs, each 8*64*512*4 B = 1 MB.
    h2* qh_h = (h2*)d_ws;
    h2* kh_h = qh_h + (size_t)NBH * NP * T;

    proj_kernel<<<512, 256, 0, stream>>>(q, k, W1, b1, qh_h, kh_h);
    score_kernel<<<512, 256, 0, stream>>>(qh_h, kh_h, W2, b2, out);
}